// Round 6
// baseline (175.633 us; speedup 1.0000x reference)
//
#include <hip/hip_runtime.h>
#include <hip/hip_bf16.h>

#define B_ 8
#define N_ 4096
#define F_ 240
#define H_ 32
#define L_ 240
#define C_ 256   /* B_*H_ merged column dim */
#define KS 2     /* stage2 K-splits */

typedef __attribute__((ext_vector_type(8))) short bf16x8;
typedef __attribute__((ext_vector_type(4))) short bf16x4;
typedef __attribute__((ext_vector_type(4))) float f32x4;

__device__ __forceinline__ short f2bf(float f) {
    union { float f; unsigned u; } v; v.f = f;
    unsigned r = (v.u + 0x7FFFu + ((v.u >> 16) & 1u)) >> 16;
    return (short)r;
}
__device__ __forceinline__ float bf2f(short s) {
    union { unsigned u; float f; } v;
    v.u = ((unsigned)(unsigned short)s) << 16;
    return v.f;
}
__device__ __forceinline__ unsigned pk2(float a, float b) {
#if defined(__has_builtin) && __has_builtin(__builtin_amdgcn_cvt_pk_bf16_f32)
    typedef __attribute__((ext_vector_type(2))) __bf16 bfv2;
    union { bfv2 v; unsigned u; } c;
    c.v = __builtin_amdgcn_cvt_pk_bf16_f32(a, b);
    return c.u;
#else
    return (unsigned)(unsigned short)f2bf(a) | (((unsigned)(unsigned short)f2bf(b)) << 16);
#endif
}

// HcF: Hc stored in MFMA B-fragment order.
// 16B unit u = ((kb*16 + ct)*2 + kp)*64 + q*16 + r holds
// Hc^T[c = ct*16 + r][k = kb*64 + kp*32 + q*8 + e], e = 0..7.
__device__ __forceinline__ long hcf_sidx(int c, int m) {
    return ((long)(((((m >> 6) * 16 + (c >> 4)) * 2 + ((m >> 5) & 1)) * 64)
                   + ((m >> 3) & 3) * 16 + (c & 15))) * 8 + (m & 7);
}

// ---------------- stage 1: Hc = x@W1 (bf16), written in B-frag order --------
__global__ __launch_bounds__(256) void stage1(const float* __restrict__ x,
                                              const float* __restrict__ W1,
                                              short* __restrict__ HcF) {
    __shared__ short w1t[32][264];
    __shared__ short xt[64][264];
    const int tid = threadIdx.x;
    const int b  = blockIdx.x >> 6;
    const int m0 = (blockIdx.x & 63) << 6;

    for (int idx = tid; idx < 120 * 32; idx += 256) {
        int fp = idx >> 5, h = idx & 31;
        unsigned u = pk2(W1[(2 * fp) * 32 + h], W1[(2 * fp + 1) * 32 + h]);
        *(unsigned*)&w1t[h][2 * fp] = u;
    }
    for (int idx = tid; idx < 32 * 8; idx += 256) {
        int h = idx >> 3, f = 240 + (idx & 7) * 2;
        *(unsigned*)&w1t[h][f] = 0;
    }
    const float* xb = x + ((long)b * N_ + m0) * F_;
    for (int idx = tid; idx < 64 * 60; idx += 256) {
        int row = idx / 60, c4 = idx % 60;
        float4 v = *(const float4*)(xb + row * F_ + c4 * 4);
        int2 s = make_int2((int)pk2(v.x, v.y), (int)pk2(v.z, v.w));
        *(int2*)&xt[row][c4 * 4] = s;
    }
    for (int idx = tid; idx < 64 * 2; idx += 256) {
        int row = idx >> 1, f = 240 + (idx & 1) * 8;
        int2 z = make_int2(0, 0);
        *(int2*)&xt[row][f] = z;
        *(int2*)&xt[row][f + 4] = z;
    }
    __syncthreads();

    const int w = tid >> 6, lane = tid & 63, q = lane >> 4, r = lane & 15;
    f32x4 acc0 = {0,0,0,0}, acc1 = {0,0,0,0};
#pragma unroll
    for (int kk = 0; kk < 8; ++kk) {
        bf16x8 bfr = *(const bf16x8*)&xt[w * 16 + r][kk * 32 + q * 8];
        bf16x8 a0  = *(const bf16x8*)&w1t[r][kk * 32 + q * 8];
        bf16x8 a1  = *(const bf16x8*)&w1t[16 + r][kk * 32 + q * 8];
        acc0 = __builtin_amdgcn_mfma_f32_16x16x32_bf16(a0, bfr, acc0, 0, 0, 0);
        acc1 = __builtin_amdgcn_mfma_f32_16x16x32_bf16(a1, bfr, acc1, 0, 0, 0);
    }
    const int m = m0 + w * 16 + r;
#pragma unroll
    for (int reg = 0; reg < 4; ++reg) {
        int h0 = q * 4 + reg;
        HcF[hcf_sidx(b * 32 + h0, m)]      = f2bf(acc0[reg]);
        HcF[hcf_sidx(b * 32 + 16 + h0, m)] = f2bf(acc1[reg]);
    }
}

// ---------------- stage 2: MT=32, BK=64, KS=2, 512 threads -------------------
// A (fp32 a -> bf16) via double-buffered frag-ordered LDS, depth-2 register
// prefetch on the HBM stream. B direct global->reg from HcF (2 MB, fits every
// XCD's L2). P = bf16 frag-linear, only 2 splits -> 4 MB round-trip.
// Frag id F = ((ks*128 + bm)*8 + w)*4 + i*2 + j ; shorts at F*256 + lane*4.
__global__ __launch_bounds__(512, 2) void stage2(const float* __restrict__ a,
                                                 const short* __restrict__ HcF,
                                                 short* __restrict__ P) {
    __shared__ short als[2][256 * 8];   // 2 bufs x 256 frags x 16B = 8 KB
    const int tid = threadIdx.x;
    const int bm = blockIdx.x >> 1;     // 0..127 m-tiles of 32
    const int ks = blockIdx.x & 1;
    const int m0 = bm << 5;
    const int kb0 = ks << 5;            // 32 k-blocks of 64 per split

    const int w = tid >> 6, lane = tid & 63, q = lane >> 4, r = lane & 15;
    const bf16x8* __restrict__ Hv = (const bf16x8*)HcF;

    f32x4 acc[2][2];
#pragma unroll
    for (int i = 0; i < 2; ++i)
#pragma unroll
        for (int j = 0; j < 2; ++j) acc[i][j] = (f32x4){0, 0, 0, 0};

    // A staging: thread stages 4 floats of frag f = tid>>1, half = tid&1.
    // frag f: i=f>>7, kp=(f>>6)&1, fq=(f>>4)&3, fr=f&15
    const int f = tid >> 1, half = tid & 1;
    const int fi = f >> 7, fkp = (f >> 6) & 1, fq = (f >> 4) & 3, fr = f & 15;
    const float* aB = a + (long)(m0 + fi * 16 + fr) * N_
                        + (kb0 << 6) + fkp * 32 + fq * 8 + half * 4;
    float pre[2][4];

#define LOAD_A(bk, t)                                                          \
    {                                                                          \
        float4 v = *(const float4*)(aB + (t) * 64);                            \
        pre[bk][0] = v.x; pre[bk][1] = v.y; pre[bk][2] = v.z; pre[bk][3] = v.w;\
    }
#define STORE_A(bk, buf)                                                       \
    {                                                                          \
        int2 p = make_int2((int)pk2(pre[bk][0], pre[bk][1]),                   \
                           (int)pk2(pre[bk][2], pre[bk][3]));                  \
        *(int2*)&als[buf][f * 8 + half * 4] = p;                               \
    }

    bf16x8 bcur[4], bnxt[4];
    LOAD_A(0, 0);
    LOAD_A(1, 1);
#pragma unroll
    for (int kp = 0; kp < 2; ++kp)
#pragma unroll
        for (int j = 0; j < 2; ++j)
            bcur[kp * 2 + j] =
                Hv[(long)((kb0 * 16 + w * 2 + j) * 2 + kp) * 64 + lane];
    STORE_A(0, 0);
    __syncthreads();

#pragma unroll 2
    for (int t = 0; t < 32; ++t) {
        const int cur = t & 1;
        if (t < 30) LOAD_A(cur, t + 2);          // bank[cur] freed last iter
        if (t < 31) {
#pragma unroll
            for (int kp = 0; kp < 2; ++kp)
#pragma unroll
                for (int j = 0; j < 2; ++j)
                    bnxt[kp * 2 + j] =
                        Hv[(long)(((kb0 + t + 1) * 16 + w * 2 + j) * 2 + kp) * 64 + lane];
        }
#pragma unroll
        for (int kp = 0; kp < 2; ++kp)
#pragma unroll
            for (int i = 0; i < 2; ++i) {
                bf16x8 af = *(const bf16x8*)&als[cur][((i * 2 + kp) * 64 + lane) * 8];
#pragma unroll
                for (int j = 0; j < 2; ++j)
                    acc[i][j] = __builtin_amdgcn_mfma_f32_16x16x32_bf16(
                        af, bcur[kp * 2 + j], acc[i][j], 0, 0, 0);
            }
        if (t < 31) {
            STORE_A(!cur, !cur);
#pragma unroll
            for (int u = 0; u < 4; ++u) bcur[u] = bnxt[u];
        }
        __syncthreads();
    }

    // coalesced 8B frag-linear stores
#pragma unroll
    for (int i = 0; i < 2; ++i)
#pragma unroll
        for (int j = 0; j < 2; ++j) {
            int2 v = make_int2((int)pk2(acc[i][j][0], acc[i][j][1]),
                               (int)pk2(acc[i][j][2], acc[i][j][3]));
            const long F = (((long)ks * 128 + bm) * 8 + w) * 4 + i * 2 + j;
            *(int2*)&P[F * 256 + lane * 4] = v;
        }
#undef LOAD_A
#undef STORE_A
}

// ---- fallback stage2: fp32 atomics into P[m][c] (if ws too small) ----------
__global__ __launch_bounds__(256, 2) void stage2_fb(const float* __restrict__ a,
                                                    const short* __restrict__ HcF,
                                                    float* __restrict__ P) {
    __shared__ short als[512 * 8];
    const int tid = threadIdx.x;
    const int bm = blockIdx.x >> 3, ks = blockIdx.x & 7;
    const int m0 = bm << 6, kb0 = ks << 3;
    const int w = tid >> 6, lane = tid & 63, q = lane >> 4, r = lane & 15;
    const bf16x8* __restrict__ Hv = (const bf16x8*)HcF;
    f32x4 acc[4][4];
#pragma unroll
    for (int i = 0; i < 4; ++i)
#pragma unroll
        for (int j = 0; j < 4; ++j) acc[i][j] = (f32x4){0, 0, 0, 0};
    const int fi = tid >> 7, fkp = (tid >> 6) & 1, fq = (tid >> 4) & 3, fr = tid & 15;
    for (int t = 0; t < 8; ++t) {
        __syncthreads();
        for (int u = 0; u < 2; ++u) {
            const float* s = a + (long)(m0 + (fi + 2 * u) * 16 + fr) * N_
                               + ((kb0 + t) << 6) + fkp * 32 + fq * 8;
            bf16x8 sv;
            for (int e = 0; e < 8; ++e) sv[e] = f2bf(s[e]);
            *(bf16x8*)&als[(tid + u * 256) * 8] = sv;
        }
        __syncthreads();
#pragma unroll
        for (int kp = 0; kp < 2; ++kp)
#pragma unroll
            for (int i = 0; i < 4; ++i) {
                bf16x8 af = *(const bf16x8*)&als[(i * 128 + kp * 64 + lane) * 8];
#pragma unroll
                for (int j = 0; j < 4; ++j) {
                    bf16x8 bfr = Hv[(long)(((kb0 + t) * 16 + w * 4 + j) * 2 + kp) * 64 + lane];
                    acc[i][j] = __builtin_amdgcn_mfma_f32_16x16x32_bf16(af, bfr, acc[i][j], 0, 0, 0);
                }
            }
    }
#pragma unroll
    for (int i = 0; i < 4; ++i)
#pragma unroll
        for (int j = 0; j < 4; ++j) {
            const int c = w * 64 + j * 16 + r;
#pragma unroll
            for (int reg = 0; reg < 4; ++reg)
                atomicAdd(&P[(long)(m0 + i * 16 + q * 4 + reg) * C_ + c], acc[i][j][reg]);
        }
}

// ---------------- stage 3: reduce 2 ks + bias + relu + (h @ W2 + b2) MFMA ----
// block g -> 16 n-rows; 512 threads; wave b owns batch b.
__global__ __launch_bounds__(512) void stage3(const short* __restrict__ P,
                                              const float* __restrict__ b1,
                                              const float* __restrict__ W2,
                                              const float* __restrict__ b2,
                                              float* __restrict__ out) {
    __shared__ short h2A[8][16][48];   // [b][row][h], padded
    __shared__ short W2T[240][56];     // [l][h], padded
    __shared__ float b2L[240];
    const int tid = threadIdx.x;
    const int g  = blockIdx.x;          // 0..255
    const int n0 = g << 4;
    const int b  = tid >> 6, lane = tid & 63, q = lane >> 4, r = lane & 15;

    for (int idx = tid; idx < 240 * 32; idx += 512) {
        int h = idx / 240, l = idx - h * 240;
        W2T[l][h] = f2bf(W2[idx]);
    }
    if (tid < 240) b2L[tid] = b2[tid];

#pragma unroll
    for (int jj = 0; jj < 2; ++jj) {
        const int h = (jj << 4) + r;
        const float bb = b1[h];
        const long F = ((long)(g >> 1) * 8 + b) * 4 + (g & 1) * 2 + jj;
        bf16x4 v0 = *(const bf16x4*)&P[F * 256 + lane * 4];
        bf16x4 v1 = *(const bf16x4*)&P[(F + 4096) * 256 + lane * 4];
#pragma unroll
        for (int e = 0; e < 4; ++e) {
            float s = bb + bf2f(v0[e]) + bf2f(v1[e]);
            h2A[b][q * 4 + e][h] = f2bf(s > 0.f ? s : 0.f);
        }
    }
    __syncthreads();

    bf16x8 af = *(const bf16x8*)&h2A[b][r][q * 8];
    float* outB = out + ((long)b * N_ + n0) * 240;
#pragma unroll
    for (int lt = 0; lt < 15; ++lt) {
        bf16x8 bf = *(const bf16x8*)&W2T[lt * 16 + r][q * 8];
        f32x4 acc = {0, 0, 0, 0};
        acc = __builtin_amdgcn_mfma_f32_16x16x32_bf16(af, bf, acc, 0, 0, 0);
        const float bias = b2L[lt * 16 + r];
#pragma unroll
        for (int reg = 0; reg < 4; ++reg)
            outB[(long)(q * 4 + reg) * 240 + lt * 16 + r] = acc[reg] + bias;
    }
}

// ---- fallback stage3: fp32 P row-major --------------------------------------
__global__ __launch_bounds__(256) void stage3_fb(const float* __restrict__ P,
                                                 const float* __restrict__ b1,
                                                 const float* __restrict__ W2,
                                                 const float* __restrict__ b2,
                                                 float* __restrict__ out) {
    __shared__ float h2[32][36];
    const int tid = threadIdx.x;
    const int g0 = blockIdx.x * 32;
    const int b  = g0 >> 12;
    const int n0 = g0 & 4095;
    {
        const int rr = tid >> 3, cg = tid & 7;
        const float* base = P + (long)(n0 + rr) * C_ + b * 32 + cg * 4;
        f32x4 v = *(const f32x4*)base;
        f32x4 bb = *(const f32x4*)(b1 + cg * 4);
#pragma unroll
        for (int e = 0; e < 4; ++e) {
            float s = v[e] + bb[e];
            h2[rr][cg * 4 + e] = s > 0.f ? s : 0.f;
        }
    }
    __syncthreads();
    if (tid < 240) {
        const int l = tid;
        float w2r[32];
#pragma unroll
        for (int h = 0; h < 32; ++h) w2r[h] = W2[h * 240 + l];
        const float bias = b2[l];
        for (int rr = 0; rr < 32; ++rr) {
            const f32x4* hv = (const f32x4*)h2[rr];
            float acc = bias;
#pragma unroll
            for (int hh = 0; hh < 8; ++hh) {
                f32x4 v = hv[hh];
                acc += v[0] * w2r[hh*4+0]; acc += v[1] * w2r[hh*4+1];
                acc += v[2] * w2r[hh*4+2]; acc += v[3] * w2r[hh*4+3];
            }
            out[(long)(g0 + rr) * 240 + l] = acc;
        }
    }
}

extern "C" void kernel_launch(void* const* d_in, const int* in_sizes, int n_in,
                              void* d_out, int out_size, void* d_ws, size_t ws_size,
                              hipStream_t stream) {
    const float* x  = (const float*)d_in[0];
    const float* a  = (const float*)d_in[1];
    const float* W1 = (const float*)d_in[2];
    const float* b1 = (const float*)d_in[3];
    const float* W2 = (const float*)d_in[4];
    const float* b2 = (const float*)d_in[5];
    float* out = (float*)d_out;

    short* HcF = (short*)d_ws;                                 // 2 MB bf16 frag-order
    void*  P   = (void*)((char*)d_ws + (size_t)C_ * N_ * 2);
    const size_t need_main = (size_t)C_ * N_ * 2 + (size_t)KS * N_ * C_ * 2;
    const size_t need_fb   = (size_t)C_ * N_ * 2 + (size_t)N_ * C_ * 4;

    stage1<<<512, 256, 0, stream>>>(x, W1, HcF);
    if (ws_size >= need_main) {
        stage2<<<256, 512, 0, stream>>>(a, HcF, (short*)P);
        stage3<<<256, 512, 0, stream>>>((const short*)P, b1, W2, b2, out);
    } else if (ws_size >= need_fb) {
        hipMemsetAsync(P, 0, (size_t)N_ * C_ * 4, stream);
        stage2_fb<<<512, 256, 0, stream>>>(a, HcF, (float*)P);
        stage3_fb<<<1024, 256, 0, stream>>>((const float*)P, b1, W2, b2, out);
    }
}

// Round 7
// 161.241 us; speedup vs baseline: 1.0893x; 1.0893x over previous
//
#include <hip/hip_runtime.h>
#include <hip/hip_bf16.h>

#define B_ 8
#define N_ 4096
#define F_ 240
#define H_ 32
#define L_ 240
#define C_ 256   /* B_*H_ merged column dim */
#define KS 8     /* stage2 K-splits */

typedef __attribute__((ext_vector_type(8))) short bf16x8;
typedef __attribute__((ext_vector_type(4))) short bf16x4;
typedef __attribute__((ext_vector_type(4))) float f32x4;

__device__ __forceinline__ short f2bf(float f) {
    union { float f; unsigned u; } v; v.f = f;
    unsigned r = (v.u + 0x7FFFu + ((v.u >> 16) & 1u)) >> 16;
    return (short)r;
}
__device__ __forceinline__ float bf2f(short s) {
    union { unsigned u; float f; } v;
    v.u = ((unsigned)(unsigned short)s) << 16;
    return v.f;
}

// HcF: Hc stored in MFMA B-fragment order.
// 16B unit u = ((kb*16 + ct)*2 + kp)*64 + q*16 + r holds
// Hc^T[c = ct*16 + r][k = kb*64 + kp*32 + q*8 + e], e = 0..7.
__device__ __forceinline__ long hcf_sidx(int c, int m) {
    return ((long)(((((m >> 6) * 16 + (c >> 4)) * 2 + ((m >> 5) & 1)) * 64)
                   + ((m >> 3) & 3) * 16 + (c & 15))) * 8 + (m & 7);
}

// ---------------- stage 1: Hc = x@W1 (bf16), written in B-frag order --------
__global__ __launch_bounds__(256) void stage1(const float* __restrict__ x,
                                              const float* __restrict__ W1,
                                              short* __restrict__ HcF) {
    __shared__ short w1t[32][264];
    __shared__ short xt[64][264];
    const int tid = threadIdx.x;
    const int b  = blockIdx.x >> 6;
    const int m0 = (blockIdx.x & 63) << 6;

    for (int idx = tid; idx < 240 * 32; idx += 256) {
        int f = idx >> 5, h = idx & 31;
        w1t[h][f] = f2bf(W1[idx]);
    }
    for (int idx = tid; idx < 32 * 16; idx += 256) {
        int h = idx >> 4, f = 240 + (idx & 15);
        w1t[h][f] = 0;
    }
    const float* xb = x + ((long)b * N_ + m0) * F_;
    for (int idx = tid; idx < 64 * 60; idx += 256) {
        int row = idx / 60, c4 = idx % 60;
        float4 v = *(const float4*)(xb + row * F_ + c4 * 4);
        bf16x4 s; s.x = f2bf(v.x); s.y = f2bf(v.y); s.z = f2bf(v.z); s.w = f2bf(v.w);
        *(bf16x4*)&xt[row][c4 * 4] = s;
    }
    for (int idx = tid; idx < 64 * 4; idx += 256) {
        int row = idx >> 2, f = 240 + (idx & 3) * 4;
        bf16x4 z = {0, 0, 0, 0};
        *(bf16x4*)&xt[row][f] = z;
    }
    __syncthreads();

    const int w = tid >> 6, lane = tid & 63, q = lane >> 4, r = lane & 15;
    f32x4 acc0 = {0,0,0,0}, acc1 = {0,0,0,0};
#pragma unroll
    for (int kk = 0; kk < 8; ++kk) {
        bf16x8 bfr = *(const bf16x8*)&xt[w * 16 + r][kk * 32 + q * 8];
        bf16x8 a0  = *(const bf16x8*)&w1t[r][kk * 32 + q * 8];
        bf16x8 a1  = *(const bf16x8*)&w1t[16 + r][kk * 32 + q * 8];
        acc0 = __builtin_amdgcn_mfma_f32_16x16x32_bf16(a0, bfr, acc0, 0, 0, 0);
        acc1 = __builtin_amdgcn_mfma_f32_16x16x32_bf16(a1, bfr, acc1, 0, 0, 0);
    }
    const int m = m0 + w * 16 + r;
#pragma unroll
    for (int reg = 0; reg < 4; ++reg) {
        int h0 = q * 4 + reg;
        HcF[hcf_sidx(b * 32 + h0, m)]      = f2bf(acc0[reg]);
        HcF[hcf_sidx(b * 32 + 16 + h0, m)] = f2bf(acc1[reg]);
    }
}

// ---------------- stage 2: frag-linear bf16 partials, MT=64, BK=64, KS=8 -----
// A (fp32 a -> bf16) via double-buffered frag-ordered LDS, DEPTH-2 register
// prefetch on the HBM stream. B direct global->reg from HcF (L2-resident).
// P layout: frag-block F = ((ks*64+bm)*4+w)*16 + i*4+j ; shorts F*256+lane*4.
__global__ __launch_bounds__(256, 2) void stage2(const float* __restrict__ a,
                                                 const short* __restrict__ HcF,
                                                 short* __restrict__ P) {
    __shared__ short als[2][512 * 8];   // 16 KB: 512 frags x 16B, double-buffered
    const int tid = threadIdx.x;
    const int bm = blockIdx.x >> 3;     // 0..63 m-tiles of 64
    const int ks = blockIdx.x & 7;      // == XCD id for L2 locality on B
    const int m0 = bm << 6;
    const int kb0 = ks << 3;            // 8 k-blocks of 64

    const int w = tid >> 6, lane = tid & 63, q = lane >> 4, r = lane & 15;
    const bf16x8* __restrict__ Hv = (const bf16x8*)HcF;

    f32x4 acc[4][4];
#pragma unroll
    for (int i = 0; i < 4; ++i)
#pragma unroll
        for (int j = 0; j < 4; ++j) acc[i][j] = (f32x4){0, 0, 0, 0};

    // A frag f: i=f>>7, kp=(f>>6)&1, q=(f>>4)&3, r=f&15. Thread owns f=tid, tid+256.
    const int fi = tid >> 7, fkp = (tid >> 6) & 1, fq = (tid >> 4) & 3, fr = tid & 15;
    const float* aB0 = a + (long)(m0 + fi * 16 + fr) * N_ + (kb0 << 6) + fkp * 32 + fq * 8;
    const float* aB1 = aB0 + 32 * N_;
    float pre[2][16];

#define LOAD_A(bk, t)                                                          \
    {                                                                          \
        const float* s0 = aB0 + (t) * 64;                                      \
        const float* s1 = aB1 + (t) * 64;                                      \
        float4 v0 = *(const float4*)s0, v1 = *(const float4*)(s0 + 4);         \
        float4 v2 = *(const float4*)s1, v3 = *(const float4*)(s1 + 4);         \
        pre[bk][0]=v0.x;  pre[bk][1]=v0.y;  pre[bk][2]=v0.z;  pre[bk][3]=v0.w; \
        pre[bk][4]=v1.x;  pre[bk][5]=v1.y;  pre[bk][6]=v1.z;  pre[bk][7]=v1.w; \
        pre[bk][8]=v2.x;  pre[bk][9]=v2.y;  pre[bk][10]=v2.z; pre[bk][11]=v2.w;\
        pre[bk][12]=v3.x; pre[bk][13]=v3.y; pre[bk][14]=v3.z; pre[bk][15]=v3.w;\
    }
#define STORE_A(bk, buf)                                                       \
    {                                                                          \
        bf16x8 s0, s1;                                                         \
        _Pragma("unroll") for (int e = 0; e < 8; ++e) {                        \
            s0[e] = f2bf(pre[bk][e]); s1[e] = f2bf(pre[bk][8 + e]);            \
        }                                                                      \
        *(bf16x8*)&als[buf][tid * 8]         = s0;                             \
        *(bf16x8*)&als[buf][(tid + 256) * 8] = s1;                             \
    }

    bf16x8 bcur[8], bnxt[8];
    LOAD_A(0, 0);
    LOAD_A(1, 1);
#pragma unroll
    for (int kp = 0; kp < 2; ++kp)
#pragma unroll
        for (int j = 0; j < 4; ++j)
            bcur[kp * 4 + j] = Hv[(long)((kb0 * 16 + w * 4 + j) * 2 + kp) * 64 + lane];
    STORE_A(0, 0);
    __syncthreads();

#pragma unroll
    for (int t = 0; t < 8; ++t) {
        const int cur = t & 1;
        if (t < 6) LOAD_A(cur, t + 2);          // bank[cur] freed last iter
        if (t < 7) {
#pragma unroll
            for (int kp = 0; kp < 2; ++kp)
#pragma unroll
                for (int j = 0; j < 4; ++j)
                    bnxt[kp * 4 + j] =
                        Hv[(long)(((kb0 + t + 1) * 16 + w * 4 + j) * 2 + kp) * 64 + lane];
        }
#pragma unroll
        for (int kp = 0; kp < 2; ++kp)
#pragma unroll
            for (int i = 0; i < 4; ++i) {
                bf16x8 af = *(const bf16x8*)&als[cur][(i * 128 + kp * 64 + lane) * 8];
#pragma unroll
                for (int j = 0; j < 4; ++j)
                    acc[i][j] = __builtin_amdgcn_mfma_f32_16x16x32_bf16(
                        af, bcur[kp * 4 + j], acc[i][j], 0, 0, 0);
            }
        if (t < 7) {
            STORE_A(!cur, !cur);                // A(t+1): regs -> LDS
#pragma unroll
            for (int u = 0; u < 8; ++u) bcur[u] = bnxt[u];
        }
        __syncthreads();
    }

    // coalesced 8B frag-linear stores
#pragma unroll
    for (int i = 0; i < 4; ++i)
#pragma unroll
        for (int j = 0; j < 4; ++j) {
            bf16x4 v;
#pragma unroll
            for (int reg = 0; reg < 4; ++reg) v[reg] = f2bf(acc[i][j][reg]);
            const long F = (((long)ks * 64 + bm) * 4 + w) * 16 + i * 4 + j;
            *(bf16x4*)&P[F * 256 + lane * 4] = v;
        }
#undef LOAD_A
#undef STORE_A
}

// ---- fallback stage2: fp32 atomics into P[m][c] (if ws too small) ----------
__global__ __launch_bounds__(256, 2) void stage2_fb(const float* __restrict__ a,
                                                    const short* __restrict__ HcF,
                                                    float* __restrict__ P) {
    __shared__ short als[512 * 8];
    const int tid = threadIdx.x;
    const int bm = blockIdx.x >> 3, ks = blockIdx.x & 7;
    const int m0 = bm << 6, kb0 = ks << 3;
    const int w = tid >> 6, lane = tid & 63, q = lane >> 4, r = lane & 15;
    const bf16x8* __restrict__ Hv = (const bf16x8*)HcF;
    f32x4 acc[4][4];
#pragma unroll
    for (int i = 0; i < 4; ++i)
#pragma unroll
        for (int j = 0; j < 4; ++j) acc[i][j] = (f32x4){0, 0, 0, 0};
    const int fi = tid >> 7, fkp = (tid >> 6) & 1, fq = (tid >> 4) & 3, fr = tid & 15;
    for (int t = 0; t < 8; ++t) {
        __syncthreads();
        for (int u = 0; u < 2; ++u) {
            const float* s = a + (long)(m0 + (fi + 2 * u) * 16 + fr) * N_
                               + ((kb0 + t) << 6) + fkp * 32 + fq * 8;
            bf16x8 sv;
            for (int e = 0; e < 8; ++e) sv[e] = f2bf(s[e]);
            *(bf16x8*)&als[(tid + u * 256) * 8] = sv;
        }
        __syncthreads();
#pragma unroll
        for (int kp = 0; kp < 2; ++kp)
#pragma unroll
            for (int i = 0; i < 4; ++i) {
                bf16x8 af = *(const bf16x8*)&als[(i * 128 + kp * 64 + lane) * 8];
#pragma unroll
                for (int j = 0; j < 4; ++j) {
                    bf16x8 bfr = Hv[(long)(((kb0 + t) * 16 + w * 4 + j) * 2 + kp) * 64 + lane];
                    acc[i][j] = __builtin_amdgcn_mfma_f32_16x16x32_bf16(af, bfr, acc[i][j], 0, 0, 0);
                }
            }
    }
#pragma unroll
    for (int i = 0; i < 4; ++i)
#pragma unroll
        for (int j = 0; j < 4; ++j) {
            const int c = w * 64 + j * 16 + r;
#pragma unroll
            for (int reg = 0; reg < 4; ++reg)
                atomicAdd(&P[(long)(m0 + i * 16 + q * 4 + reg) * C_ + c], acc[i][j][reg]);
        }
}

// ---------------- stage 3: reduce ks + bias + relu + (h @ W2 + b2) via MFMA --
// 512 blocks x 256 threads: block (g, bh) -> 16 n-rows x 4 batches.
// Wave w2 owns batch b = bh*4 + w2.
__global__ __launch_bounds__(256) void stage3(const short* __restrict__ P,
                                              const float* __restrict__ b1,
                                              const float* __restrict__ W2,
                                              const float* __restrict__ b2,
                                              float* __restrict__ out) {
    __shared__ short h2A[4][16][48];   // [b-local][row][h], padded
    __shared__ short W2T[240][56];     // [l][h], padded
    __shared__ float b2L[240];
    const int tid = threadIdx.x;
    const int g  = blockIdx.x >> 1;     // 0..255 n-groups of 16
    const int bh = blockIdx.x & 1;      // batch half
    const int bm = g >> 2, i = g & 3;
    const int n0 = g << 4;
    const int w2 = tid >> 6, lane = tid & 63, q = lane >> 4, r = lane & 15;
    const int b  = bh * 4 + w2;
    const int w  = b >> 1, jp = b & 1;

    for (int idx = tid; idx < 240 * 32; idx += 256) {
        int h = idx / 240, l = idx - h * 240;
        W2T[l][h] = f2bf(W2[idx]);
    }
    if (tid < 240) b2L[tid] = b2[tid];

#pragma unroll
    for (int jj = 0; jj < 2; ++jj) {
        const int j = jp * 2 + jj;
        const int h = (jj << 4) + r;
        const float bb = b1[h];
        float s[4] = {bb, bb, bb, bb};
        const long F0 = ((long)bm * 4 + w) * 16 + i * 4 + j;
#pragma unroll
        for (int ks = 0; ks < 8; ++ks) {
            bf16x4 v = *(const bf16x4*)&P[(F0 + (long)ks * 4096) * 256 + lane * 4];
#pragma unroll
            for (int e = 0; e < 4; ++e) s[e] += bf2f(v[e]);
        }
#pragma unroll
        for (int e = 0; e < 4; ++e) {
            float z = s[e] > 0.f ? s[e] : 0.f;
            h2A[w2][q * 4 + e][h] = f2bf(z);
        }
    }
    __syncthreads();

    bf16x8 af = *(const bf16x8*)&h2A[w2][r][q * 8];
    float* outB = out + ((long)b * N_ + n0) * 240;
#pragma unroll
    for (int lt = 0; lt < 15; ++lt) {
        bf16x8 bf = *(const bf16x8*)&W2T[lt * 16 + r][q * 8];
        f32x4 acc = {0, 0, 0, 0};
        acc = __builtin_amdgcn_mfma_f32_16x16x32_bf16(af, bf, acc, 0, 0, 0);
        const float bias = b2L[lt * 16 + r];
#pragma unroll
        for (int reg = 0; reg < 4; ++reg)
            outB[(long)(q * 4 + reg) * 240 + lt * 16 + r] = acc[reg] + bias;
    }
}

// ---- fallback stage3: fp32 P row-major --------------------------------------
__global__ __launch_bounds__(256) void stage3_fb(const float* __restrict__ P,
                                                 const float* __restrict__ b1,
                                                 const float* __restrict__ W2,
                                                 const float* __restrict__ b2,
                                                 float* __restrict__ out) {
    __shared__ float h2[32][36];
    const int tid = threadIdx.x;
    const int g0 = blockIdx.x * 32;
    const int b  = g0 >> 12;
    const int n0 = g0 & 4095;
    {
        const int rr = tid >> 3, cg = tid & 7;
        const float* base = P + (long)(n0 + rr) * C_ + b * 32 + cg * 4;
        f32x4 v = *(const f32x4*)base;
        f32x4 bb = *(const f32x4*)(b1 + cg * 4);
#pragma unroll
        for (int e = 0; e < 4; ++e) {
            float s = v[e] + bb[e];
            h2[rr][cg * 4 + e] = s > 0.f ? s : 0.f;
        }
    }
    __syncthreads();
    if (tid < 240) {
        const int l = tid;
        float w2r[32];
#pragma unroll
        for (int h = 0; h < 32; ++h) w2r[h] = W2[h * 240 + l];
        const float bias = b2[l];
        for (int rr = 0; rr < 32; ++rr) {
            const f32x4* hv = (const f32x4*)h2[rr];
            float acc = bias;
#pragma unroll
            for (int hh = 0; hh < 8; ++hh) {
                f32x4 v = hv[hh];
                acc += v[0] * w2r[hh*4+0]; acc += v[1] * w2r[hh*4+1];
                acc += v[2] * w2r[hh*4+2]; acc += v[3] * w2r[hh*4+3];
            }
            out[(long)(g0 + rr) * 240 + l] = acc;
        }
    }
}

extern "C" void kernel_launch(void* const* d_in, const int* in_sizes, int n_in,
                              void* d_out, int out_size, void* d_ws, size_t ws_size,
                              hipStream_t stream) {
    const float* x  = (const float*)d_in[0];
    const float* a  = (const float*)d_in[1];
    const float* W1 = (const float*)d_in[2];
    const float* b1 = (const float*)d_in[3];
    const float* W2 = (const float*)d_in[4];
    const float* b2 = (const float*)d_in[5];
    float* out = (float*)d_out;

    short* HcF = (short*)d_ws;                                 // 2 MB bf16 frag-order
    void*  P   = (void*)((char*)d_ws + (size_t)C_ * N_ * 2);
    const size_t need_main = (size_t)C_ * N_ * 2 + (size_t)KS * N_ * C_ * 2;
    const size_t need_fb   = (size_t)C_ * N_ * 2 + (size_t)N_ * C_ * 4;

    stage1<<<512, 256, 0, stream>>>(x, W1, HcF);
    if (ws_size >= need_main) {
        stage2<<<512, 256, 0, stream>>>(a, HcF, (short*)P);
        stage3<<<512, 256, 0, stream>>>((const short*)P, b1, W2, b2, out);
    } else if (ws_size >= need_fb) {
        hipMemsetAsync(P, 0, (size_t)N_ * C_ * 4, stream);
        stage2_fb<<<512, 256, 0, stream>>>(a, HcF, (float*)P);
        stage3_fb<<<1024, 256, 0, stream>>>((const float*)P, b1, W2, b2, out);
    }
}